// Round 11
// baseline (1290.027 us; speedup 1.0000x reference)
//
#include <hip/hip_runtime.h>

#define TT    1024   // timesteps
#define BATCH 2048
#define NI    6      // input dim
#define NH    38     // hidden
#define NG    152    // 4*NH
#define NCLS  8      // classes
#define NB    8      // batches per block -> grid 256 = 1 block/CU
#define BLK   640    // 10 waves: 5 L1 + 5 L2, 2 M-tiles each
#define UK    100    // unified K stride (f16): h1@0..37, x@40..45, h2@48..85, pad
#define XK    40     // x k-offset
#define H2K   48     // h2 k-offset
#define RD    16     // x-ring depth (steps), two 8-step banks ping-pong

typedef _Float16 f16;
typedef _Float16 f16x4 __attribute__((ext_vector_type(4)));
typedef _Float16 f16x8 __attribute__((ext_vector_type(8)));
typedef float    f32x4 __attribute__((ext_vector_type(4)));

__device__ __forceinline__ float fsig(float v)  { return __fdividef(1.0f, 1.0f + __expf(-v)); }
__device__ __forceinline__ float ftanh(float v) { return 1.0f - __fdividef(2.0f, 1.0f + __expf(2.0f*v)); }

// ---- weight element in gate-interleaved unified K-space ----
// row r = 4*u + g -> one unit's i,f,g,o land in one lane's 4 C-regs
// (C/D layout col=lane&15, row=(lane>>4)*4+reg — R9-verified end-to-end).
__device__ __forceinline__ float wget1(const float* Wih0, const float* Whh0, int r, int k) {
    if (r >= NG) return 0.0f;
    const int u = r >> 2, g = r & 3;
    if (k < NH) return Whh0[(size_t)(g*NH + u)*NH + k];
    if (k >= XK && k < XK + NI) return Wih0[(size_t)(g*NH + u)*NI + (k - XK)];
    return 0.0f;
}
__device__ __forceinline__ float wget2(const float* Wih1, const float* Whh1, int r, int k) {
    if (r >= NG) return 0.0f;
    const int u = r >> 2, g = r & 3;
    if (k < NH) return Wih1[(size_t)(g*NH + u)*NH + k];          // h1 part
    if (k >= H2K && k < H2K + NH) return Whh1[(size_t)(g*NH + u)*NH + (k - H2K)]; // h2 part
    return 0.0f;   // zeros at 38..47 kill the x slots for L2
}

// k-slot convention IDENTICAL for A and B (permutation cancels inside MFMA):
// elem e of lane l covers k = 32F + (e<4 ? qq*4+e : 16+qq*4+e-4), qq=l>>4.
__device__ __forceinline__ f16x8 ldA1(const float* Wih0, const float* Whh0,
                                      int Tg, int F, int m16, int qq) {
    f16x8 r;
    #pragma unroll
    for (int e = 0; e < 8; ++e) {
        const int kk = 32*F + ((e < 4) ? (qq*4 + e) : (16 + qq*4 + e - 4));
        r[e] = (f16)wget1(Wih0, Whh0, 16*Tg + m16, kk);
    }
    return r;
}
__device__ __forceinline__ f16x8 ldA2(const float* Wih1, const float* Whh1,
                                      int Tg, int F, int m16, int qq) {
    f16x8 r;
    #pragma unroll
    for (int e = 0; e < 8; ++e) {
        const int kk = 32*F + ((e < 4) ? (qq*4 + e) : (16 + qq*4 + e - 4));
        r[e] = (f16)wget2(Wih1, Whh1, 16*Tg + m16, kk);
    }
    return r;
}

// B fragment: batch-major rows -> two contiguous f16x4 LDS reads
__device__ __forceinline__ f16x8 ldB(const f16* rb, int off) {
    const f16x4 lo = *(const f16x4*)(rb + off);
    const f16x4 hi = *(const f16x4*)(rb + off + 16);
    f16x8 r;
    r[0]=lo[0]; r[1]=lo[1]; r[2]=lo[2]; r[3]=lo[3];
    r[4]=hi[0]; r[5]=hi[1]; r[6]=hi[2]; r[7]=hi[3];
    return r;
}

#define MFMA16(A, B, C) __builtin_amdgcn_mfma_f32_16x16x32_f16(A, B, C, 0, 0, 0)

#define PWCORE(A, CREG) \
    const float ig = fsig((A)[0] + bsv0), fg = fsig((A)[1] + bsv1); \
    const float gg = ftanh((A)[2] + bsv2), og = fsig((A)[3] + bsv3); \
    const float cc = fg * (CREG) + ig * gg; (CREG) = cc; \
    const f16 hv = (f16)(og * ftanh(cc));

// lgkm-only barrier (HK pattern): LDS writes drained, global prefetch loads
// stay in flight across iterations (the whole point of the deep x-ring).
#define LBAR() \
    asm volatile("s_waitcnt lgkmcnt(0)" ::: "memory"); \
    __builtin_amdgcn_s_barrier(); \
    asm volatile("" ::: "memory"); \
    __builtin_amdgcn_sched_barrier(0);

__global__ __launch_bounds__(BLK, 1) void lstm2_kernel(
    const float* __restrict__ x,
    const float* __restrict__ Wih0, const float* __restrict__ Whh0, const float* __restrict__ b0,
    const float* __restrict__ Wih1, const float* __restrict__ Whh1, const float* __restrict__ b1,
    const float* __restrict__ Wc,   const float* __restrict__ bc,
    float* __restrict__ out)
{
    __shared__ __align__(16) f16 ubuf[2][16][UK];   // 6400 B unified B-buffer
    __shared__ __align__(16) f16 xring[RD][48];     // 1536 B x ring (f16)
    __shared__ float ldspad[20160];                 // 80640 B -> total 88576 B
                                                    // (keeps the 1-block/CU 256-reg regime)

    const int tid   = threadIdx.x;
    const int bbase = blockIdx.x * NB;
    const int wid   = tid >> 6, lane = tid & 63;
    const int n     = lane & 15, qq = lane >> 4;

    if (bc[0] > 3.0e38f) ldspad[tid] = x[tid];   // keep pad alive (runtime-false)

    // zero both slots (pads stay 0 forever)
    {
        int* p = (int*)&ubuf[0][0][0];
        for (int idx = tid; idx < 2*16*UK/2; idx += BLK) p[idx] = 0;
    }
    __syncthreads();

    const bool isL1 = (wid < 5);
    const int  T0   = 2 * (isL1 ? wid : wid - 5);
    const int  u0   = 4*T0 + qq, u1 = u0 + 4;
    const bool wen0 = (u0 < NH) && (n < NB);
    const bool wen1 = (u1 < NH) && (n < NB);

    // ---- persistent A-fragments ----
    f16x8 w00, w01, w02, w10, w11, w12;
    float bs00=0.f,bs01=0.f,bs02=0.f,bs03=0.f, bs10=0.f,bs11=0.f,bs12=0.f,bs13=0.f;
    {
        f16x8 z8;
        #pragma unroll
        for (int e = 0; e < 8; ++e) z8[e] = (f16)0;
        w02 = z8; w12 = z8;
        if (isL1) {
            w00 = ldA1(Wih0, Whh0, T0,   0, n, qq);
            w01 = ldA1(Wih0, Whh0, T0,   1, n, qq);
            w10 = ldA1(Wih0, Whh0, T0+1, 0, n, qq);
            w11 = ldA1(Wih0, Whh0, T0+1, 1, n, qq);
            if (u0 < NH) { bs00=b0[u0]; bs01=b0[NH+u0]; bs02=b0[2*NH+u0]; bs03=b0[3*NH+u0]; }
            if (u1 < NH) { bs10=b0[u1]; bs11=b0[NH+u1]; bs12=b0[2*NH+u1]; bs13=b0[3*NH+u1]; }
        } else {
            w00 = ldA2(Wih1, Whh1, T0,   0, n, qq);
            w01 = ldA2(Wih1, Whh1, T0,   1, n, qq);
            w02 = ldA2(Wih1, Whh1, T0,   2, n, qq);
            w10 = ldA2(Wih1, Whh1, T0+1, 0, n, qq);
            w11 = ldA2(Wih1, Whh1, T0+1, 1, n, qq);
            w12 = ldA2(Wih1, Whh1, T0+1, 2, n, qq);
            if (u0 < NH) { bs00=b1[u0]; bs01=b1[NH+u0]; bs02=b1[2*NH+u0]; bs03=b1[3*NH+u0]; }
            if (u1 < NH) { bs10=b1[u1]; bs11=b1[NH+u1]; bs12=b1[2*NH+u1]; bs13=b1[3*NH+u1]; }
        }
    }

    // ---- B-row / write pointers (ONE name set across roles — R3 lesson) ----
    const f16* rowp0 = &ubuf[0][n][0];
    const f16* rowp1 = &ubuf[1][n][0];
    f16 *wpA0, *wpA1, *wpB0, *wpB1;
    if (isL1) {
        wpA0 = &ubuf[0][n][u0];       wpA1 = &ubuf[1][n][u0];
        wpB0 = &ubuf[0][n][u1];       wpB1 = &ubuf[1][n][u1];
    } else {
        wpA0 = &ubuf[0][n][H2K+u0];   wpA1 = &ubuf[1][n][H2K+u0];
        wpB0 = &ubuf[0][n][H2K+u1];   wpB1 = &ubuf[1][n][H2K+u1];
    }

    // ---- x prefetch role: wave 0 lanes 0..47; deep ring, 8-step batches ----
    const bool isPF = (tid < NB * NI);
    const int  pb = tid / NI, pj = tid % NI;
    const float* xgbase = x + (size_t)(bbase + pb)*TT*NI + pj;
    f16* ringl = &xring[0][pb*NI + pj];
    f16 *pwx0 = &ubuf[0][pb][XK + pj], *pwx1 = &ubuf[1][pb][XK + pj];
    float pl0=0.f,pl1=0.f,pl2=0.f,pl3=0.f,pl4=0.f,pl5=0.f,pl6=0.f,pl7=0.f;

    if (isPF) {
        // x(0) -> slot 1 (iter 0 reads rs=1); ring slots 1..7 <- x(1..7)
        *pwx1 = (f16)xgbase[0];
        #pragma unroll
        for (int t = 1; t <= 7; ++t) ringl[t*48] = (f16)xgbase[(size_t)t*NI];
    }

    float c0 = 0.0f, c1 = 0.0f;   // f32 cell states

    __syncthreads();

    #pragma unroll 1
    for (int i = 0; i <= TT; ++i) {
        const int s = i & 1;

        // refill issue: every 8 iters load x(i+8..i+15) (guarded) — consumed 6 iters later
        if (isPF && (i & 7) == 0) {
            const int tb = i + 8;
            pl0 = (tb+0 < TT) ? xgbase[(size_t)(tb+0)*NI] : 0.f;
            pl1 = (tb+1 < TT) ? xgbase[(size_t)(tb+1)*NI] : 0.f;
            pl2 = (tb+2 < TT) ? xgbase[(size_t)(tb+2)*NI] : 0.f;
            pl3 = (tb+3 < TT) ? xgbase[(size_t)(tb+3)*NI] : 0.f;
            pl4 = (tb+4 < TT) ? xgbase[(size_t)(tb+4)*NI] : 0.f;
            pl5 = (tb+5 < TT) ? xgbase[(size_t)(tb+5)*NI] : 0.f;
            pl6 = (tb+6 < TT) ? xgbase[(size_t)(tb+6)*NI] : 0.f;
            pl7 = (tb+7 < TT) ? xgbase[(size_t)(tb+7)*NI] : 0.f;
        }

        if (isL1) {
            if (i < TT) {
                const f16* rb = s ? rowp0 : rowp1;      // read slot rs = s^1
                const f16x8 B0 = ldB(rb, 4*qq);
                const f16x8 B1 = ldB(rb, 32 + 4*qq);
                f32x4 a0 = {0.f,0.f,0.f,0.f}, a1 = {0.f,0.f,0.f,0.f};
                a0 = MFMA16(w00, B0, a0);
                a0 = MFMA16(w01, B1, a0);
                a1 = MFMA16(w10, B0, a1);
                a1 = MFMA16(w11, B1, a1);
                {
                    const float bsv0=bs00, bsv1=bs01, bsv2=bs02, bsv3=bs03;
                    PWCORE(a0, c0)
                    if (wen0) *(s ? wpA1 : wpA0) = hv;
                }
                {
                    const float bsv0=bs10, bsv1=bs11, bsv2=bs12, bsv3=bs13;
                    PWCORE(a1, c1)
                    if (wen1) *(s ? wpB1 : wpB0) = hv;
                }
            }
        } else {
            if (i >= 1) {
                const f16* rb = s ? rowp0 : rowp1;
                const f16x8 B0 = ldB(rb, 4*qq);
                const f16x8 B1 = ldB(rb, 32 + 4*qq);
                const f16x8 B2 = ldB(rb, 64 + 4*qq);
                f32x4 a0 = {0.f,0.f,0.f,0.f}, a1 = {0.f,0.f,0.f,0.f};
                a0 = MFMA16(w00, B0, a0);
                a0 = MFMA16(w01, B1, a0);
                a0 = MFMA16(w02, B2, a0);
                a1 = MFMA16(w10, B0, a1);
                a1 = MFMA16(w11, B1, a1);
                a1 = MFMA16(w12, B2, a1);
                {
                    const float bsv0=bs00, bsv1=bs01, bsv2=bs02, bsv3=bs03;
                    PWCORE(a0, c0)
                    if (wen0) *(s ? wpA1 : wpA0) = hv;
                }
                {
                    const float bsv0=bs10, bsv1=bs11, bsv2=bs12, bsv3=bs13;
                    PWCORE(a1, c1)
                    if (wen1) *(s ? wpB1 : wpB0) = hv;
                }
            }
        }

        if (isPF) {
            // consume: ring -> x slots of write-slot s (read next iter)
            if (i + 1 < TT) {
                const f16 xv = ringl[((i + 1) & (RD-1)) * 48];
                *(s ? pwx1 : pwx0) = xv;
            }
            // refill write: 6 iters after issue; slots (i+2..i+9)&15 = opposite bank
            if ((i & 7) == 6) {
                const int tb = i + 2;
                ringl[((tb+0)&(RD-1))*48] = (f16)pl0;
                ringl[((tb+1)&(RD-1))*48] = (f16)pl1;
                ringl[((tb+2)&(RD-1))*48] = (f16)pl2;
                ringl[((tb+3)&(RD-1))*48] = (f16)pl3;
                ringl[((tb+4)&(RD-1))*48] = (f16)pl4;
                ringl[((tb+5)&(RD-1))*48] = (f16)pl5;
                ringl[((tb+6)&(RD-1))*48] = (f16)pl6;
                ringl[((tb+7)&(RD-1))*48] = (f16)pl7;
            }
        }

        LBAR()
    }

    // epilogue: out = h2(TT-1) @ Wc.T + bc ; final h2 in ubuf[0][b][H2K+.]
    if (tid < NB * NCLS) {
        const int b = tid >> 3, c = tid & 7;
        float a = bc[c];
        #pragma unroll
        for (int k = 0; k < NH; ++k)
            a += Wc[c*NH + k] * (float)ubuf[0][b][H2K + k];
        out[(size_t)(bbase + b)*NCLS + c] = a;
    }
    if (bc[0] > 3.0e38f) out[tid] = ldspad[BLK - tid];
}

extern "C" void kernel_launch(void* const* d_in, const int* in_sizes, int n_in,
                              void* d_out, int out_size, void* d_ws, size_t ws_size,
                              hipStream_t stream) {
    const float* x    = (const float*)d_in[0];
    const float* Wih0 = (const float*)d_in[1];
    const float* Whh0 = (const float*)d_in[2];
    const float* b0   = (const float*)d_in[3];
    const float* Wih1 = (const float*)d_in[4];
    const float* Whh1 = (const float*)d_in[5];
    const float* b1   = (const float*)d_in[6];
    const float* Wc   = (const float*)d_in[7];
    const float* bc   = (const float*)d_in[8];
    float* out = (float*)d_out;

    dim3 grid(BATCH / NB);
    dim3 block(BLK);
    hipLaunchKernelGGL(lstm2_kernel, grid, block, 0, stream,
                       x, Wih0, Whh0, b0, Wih1, Whh1, b1, Wc, bc, out);
}